// Round 2
// baseline (53.830 us; speedup 1.0000x reference)
//
#include <hip/hip_runtime.h>

// BurstCoding: out[b,t,s] = ((t % period) < burst_length) && ((t / period) < floor(clip(x[b,s],0,1)*max_bursts))
// x: [B=16, 3, 224, 224] f32, out: [B, T=32, 3, 224, 224] f32.
//
// Per-OUTPUT-thread mapping: blockIdx.y picks the (b,t) plane, blockIdx.x+tid
// walks the spatial dim -> one perfectly linear write stream per plane
// (memset-like, target ~6.9 TB/s like the harness fillBuffer).
// 20/32 planes (t%period >= burst_length) are all-zero regardless of x:
// pure store, no load. Active planes re-read x from L2/L3 (x is 9.6 MB).
//
// Predicate simplification (exact): bidx < floor(clamp(x,0,1)*maxb)
//   <=> clamp(x,0,1)*maxb >= bidx+1   (y>=0, integer rhs)
// so each element is clamp+mul+compare, no floor/cvt.

__global__ __launch_bounds__(256) void burst_coding_kernel(
    const float* __restrict__ x, float* __restrict__ out,
    const int* __restrict__ p_bl, const int* __restrict__ p_ibi,
    int T, int S4)
{
    const int bl     = *p_bl;            // burst_length (scalar broadcast)
    const int period = bl + *p_ibi;      // burst_length + interburst_interval
    const int maxb   = T / period;       // max_bursts

    const int bt   = blockIdx.y;         // b*T + t
    const int t    = bt % T;
    const int b    = bt / T;
    const int tm   = t % period;
    const int bidx = t / period;

    const int s4 = blockIdx.x * blockDim.x + threadIdx.x;
    if (s4 >= S4) return;

    float4* op = reinterpret_cast<float4*>(out) + (long)bt * S4 + s4;

    if (tm >= bl || bidx >= maxb) {
        // inactive plane: all zeros, no x read — pure store stream
        *op = make_float4(0.f, 0.f, 0.f, 0.f);
        return;
    }

    const float mbf  = (float)maxb;
    const float bthr = (float)(bidx + 1);
    const float4 xv  = reinterpret_cast<const float4*>(x)[(long)b * S4 + s4];

    float4 v;
    v.x = (fminf(fmaxf(xv.x, 0.f), 1.f) * mbf >= bthr) ? 1.f : 0.f;
    v.y = (fminf(fmaxf(xv.y, 0.f), 1.f) * mbf >= bthr) ? 1.f : 0.f;
    v.z = (fminf(fmaxf(xv.z, 0.f), 1.f) * mbf >= bthr) ? 1.f : 0.f;
    v.w = (fminf(fmaxf(xv.w, 0.f), 1.f) * mbf >= bthr) ? 1.f : 0.f;
    *op = v;
}

extern "C" void kernel_launch(void* const* d_in, const int* in_sizes, int n_in,
                              void* d_out, int out_size, void* d_ws, size_t ws_size,
                              hipStream_t stream) {
    const float* x   = (const float*)d_in[0];
    // d_in[1] = timesteps (derived on host from sizes instead)
    const int* p_bl  = (const int*)d_in[2];  // burst_length
    const int* p_ibi = (const int*)d_in[3];  // interburst_interval
    float* out = (float*)d_out;

    const long N  = (long)in_sizes[0];          // B * S
    const int  T  = (int)((long)out_size / N);  // = 32
    const int  S  = 3 * 224 * 224;              // spatial elems per batch (reference setup)
    const int  S4 = S / 4;                      // 37632 float4 per plane
    const int  B  = (int)(N / S);               // 16

    const int threads = 256;
    dim3 grid((S4 + threads - 1) / threads,     // 147 blocks along spatial
              (unsigned)(B * T));               // 512 planes

    burst_coding_kernel<<<grid, dim3(threads), 0, stream>>>(
        x, out, p_bl, p_ibi, T, S4);
}